// Round 10
// baseline (996.432 us; speedup 1.0000x reference)
//
#include <hip/hip_runtime.h>
#include <math.h>

typedef float  fx4  __attribute__((ext_vector_type(4)));
typedef short  bfx8 __attribute__((ext_vector_type(8)));

// Bilinear weights exactly mirroring the reference resize_bilinear.
__device__ __forceinline__ void bl_w(int o, int O, int I, int& i0, int& i1, float& w) {
    float r = (float)((double)I / (double)O);
    float f = (o + 0.5f) * r - 0.5f;
    f = fminf(fmaxf(f, 0.0f), (float)(I - 1));
    int a = (int)floorf(f);
    i0 = a;
    i1 = min(a + 1, I - 1);
    w = f - (float)a;
}

// Ratio-precomputed variant (r = I/O as f32, from meta).
__device__ __forceinline__ void bl_w_r(int o, float r, int I, int& i0, int& i1, float& w) {
    float f = (o + 0.5f) * r - 0.5f;
    f = fminf(fmaxf(f, 0.0f), (float)(I - 1));
    int a = (int)floorf(f);
    i0 = a;
    i1 = min(a + 1, I - 1);
    w = f - (float)a;
}

__device__ __forceinline__ unsigned int bf16rne(float f) {
    unsigned int x = __builtin_bit_cast(unsigned int, f);
    return ((x + 0x7fffu + ((x >> 16) & 1u)) >> 16) & 0xffffu;
}

// HW packed convert: D = bf16(lo) | bf16(hi)<<16 (RNE).
__device__ __forceinline__ unsigned int pk_bf16(float lo, float hi) {
    unsigned int r;
    asm("v_cvt_pk_bf16_f32 %0, %1, %2" : "=v"(r) : "v"(lo), "v"(hi));
    return r;
}

// Meta ints: [0]=mh [1]=mw ; [2+4n..]=t,l,ch,cw ; [2+4N+2s..]=fh,fw.
// Meta floats (as int bits) at fo2=2+4N+6: per sc: mw/fw, mh/fh (6);
// then per n: cww/mw, chh/mh (2N).
__global__ void k_meta(const int* __restrict__ tlbr, const int* __restrict__ p_imgh,
                       const int* __restrict__ p_imgw, int B, int N, int ms,
                       int* __restrict__ meta) {
    if (blockIdx.x != 0 || threadIdx.x != 0) return;
    const int HFs[2] = {128, 64};
    const double SC[2] = {0.9, 1.1};
    int img_h = *p_imgh, img_w = *p_imgw;
    for (int b = 0; b < B; ++b)
      for (int lvl = 0; lvl < 2; ++lvl) {
        int HF = HFs[lvl], WF = HFs[lvl];
        double sh = (double)HF / (double)img_h;
        double sw = (double)WF / (double)img_w;
        int* m = meta + (b*2 + lvl)*ms;
        int mh = 0, mw = 0;
        for (int n = 0; n < N; ++n) {
            const int* bx = tlbr + ((size_t)(b*N) + n)*4;
            int t  = max((int)floor((double)bx[0]*sh), 0);
            int l  = max((int)floor((double)bx[1]*sw), 0);
            int bb = min((int)ceil((double)bx[2]*sh) + 1, HF);
            int rr = min((int)ceil((double)bx[3]*sw) + 1, WF);
            int chh = bb - t, cww = rr - l;
            m[2+4*n+0] = t; m[2+4*n+1] = l; m[2+4*n+2] = chh; m[2+4*n+3] = cww;
            mh = max(mh, chh); mw = max(mw, cww);
        }
        m[0] = mh; m[1] = mw;
        int fo = 2 + 4*N;
        m[fo+0] = mh; m[fo+1] = mw;
        for (int s = 0; s < 2; ++s) {
            int hs  = (int)ceil((double)mh * SC[s]); if (hs  <= 1) hs  = mh;
            int wsv = (int)ceil((double)mw * SC[s]); if (wsv <= 1) wsv = mw;
            m[fo+2+2*s] = hs; m[fo+2+2*s+1] = wsv;
        }
        int fo2 = fo + 6;
        for (int s = 0; s < 3; ++s) {
            int fh = m[fo+2*s], fw = m[fo+2*s+1];
            m[fo2+2*s]   = __float_as_int((float)((double)mw / (double)fw));
            m[fo2+2*s+1] = __float_as_int((float)((double)mh / (double)fh));
        }
        for (int n = 0; n < N; ++n) {
            m[fo2+6+2*n]   = __float_as_int((float)((double)m[2+4*n+3] / (double)mw));
            m[fo2+6+2*n+1] = __float_as_int((float)((double)m[2+4*n+2] / (double)mh));
        }
      }
}

// Fused crop-resize + filter-resize, MFMA A-frag swizzled order.
// One thread = one (lb,s,g,m) = 4 u32s (full 8-ky j-column): x-chain computed
// once, stored as one uint4. k-step s = (c,kxg,kyg); kx = kxg*4+g, ky=kyg*8+j.
template<int C, int KH, int KW, int NKYG>
__global__ void k_filters(const float* __restrict__ feat_all, const int* __restrict__ meta,
                          unsigned short* __restrict__ Wswz, int b0, int chunkB,
                          int N, int lvl, int ms, int HF, int WF) {
    constexpr int KWG = KW/4;
    constexpr int KT  = C*KWG*NKYG;
    long long tau = (long long)blockIdx.x*256 + threadIdx.x;
    long long total = (long long)chunkB * KT * 64;
    if (tau >= total) return;
    int m  = (int)(tau & 15);
    int g  = (int)((tau >> 4) & 3);
    long long rest = tau >> 6;
    int s  = (int)(rest % KT);
    int lb = (int)(rest / KT);
    int kyg = s % NKYG; int s2 = s / NKYG;
    int kxg = s2 % KWG;
    int c   = s2 / KWG;
    int kx  = kxg*4 + g;
    int ky0 = kyg*8;
    uint4 outv = make_uint4(0, 0, 0, 0);
    unsigned int* ow = (unsigned int*)&outv;
    int sc = m / N, n = m - sc*N;
    if (sc < 3) {
        int b = b0 + lb;
        const int* mt = meta + (b*2 + lvl)*ms;
        int mh = mt[0], mw = mt[1];
        int t = mt[2+4*n], l = mt[3+4*n], chh = mt[4+4*n], cww = mt[5+4*n];
        int fo = 2 + 4*N;
        int fh = mt[fo + 2*sc], fw = mt[fo + 2*sc + 1];
        int fo2 = fo + 6;
        float r1 = __int_as_float(mt[fo2+2*sc]);      // mw/fw
        float r2 = __int_as_float(mt[fo2+2*sc+1]);    // mh/fh
        float r3 = __int_as_float(mt[fo2+6+2*n]);     // cww/mw
        float r4 = __int_as_float(mt[fo2+6+2*n+1]);   // chh/mh
        int offy = KH/2 - fh/2, offx = KW/2 - fw/2;
        int fx = kx - offx;
        if (fx >= 0 && fx < fw) {
            const float* src = feat_all + ((size_t)b*C + c)*HF*WF;
            int px0, px1; float wx;  bl_w_r(fx, r1, mw, px0, px1, wx);
            int ax0, ax1; float awx; bl_w_r(px0, r3, cww, ax0, ax1, awx);
            int bx0, bx1; float bwx; bl_w_r(px1, r3, cww, bx0, bx1, bwx);
            #pragma unroll
            for (int jj = 0; jj < 8; ++jj) {
                int fy = ky0 + jj - offy;
                if (fy >= 0 && fy < fh) {
                    int py0, py1; float wy; bl_w_r(fy, r2, mh, py0, py1, wy);
                    float pv[2][2];
                    #pragma unroll
                    for (int pi = 0; pi < 2; ++pi) {
                        int py = pi ? py1 : py0;
                        int cy0, cy1; float cwy; bl_w_r(py, r4, chh, cy0, cy1, cwy);
                        const float* q0 = src + (size_t)(t + cy0)*WF + l;
                        const float* q1 = src + (size_t)(t + cy1)*WF + l;
                        pv[pi][0] = (q0[ax0]*(1.f-cwy) + q1[ax0]*cwy)*(1.f-awx)
                                  + (q0[ax1]*(1.f-cwy) + q1[ax1]*cwy)*awx;
                        pv[pi][1] = (q0[bx0]*(1.f-cwy) + q1[bx0]*cwy)*(1.f-bwx)
                                  + (q0[bx1]*(1.f-cwy) + q1[bx1]*cwy)*bwx;
                    }
                    float v = (pv[0][0]*(1.f-wy) + pv[1][0]*wy)*(1.f-wx)
                            + (pv[0][1]*(1.f-wy) + pv[1][1]*wy)*wx;
                    ow[jj >> 1] |= bf16rne(v) << (16*(jj & 1));
                }
            }
        }
    }
    ((uint4*)Wswz)[tau] = outv;
}

// MFMA implicit-GEMM xcorr, split-K, NT px-tiles x NDY row-groups per block.
// CC=1 channel/chunk; channel order rotated per block (convoy stagger);
// A-frags software-prefetched across the MFMA cluster (independent of LDS
// barriers). Column-major bf16 LDS, RSTR odd x 16B (conflict-free b128 R+W).
template<int C, int KS, int KH, int KW, int H, int W, int NKYG, int NDY, int NT,
         int RSTR, int NCOL, int P>
__global__ __launch_bounds__(256, 4) void k_mfconv(
        const float* __restrict__ feat_all, const unsigned short* __restrict__ Wswz,
        float* __restrict__ part, int b0, int Btot, int N, int nks) {
    constexpr int KWG   = KW/4;
    constexpr int NROWS = KH + (NDY-1)*8;
    constexpr int NRT   = NROWS/8;
    constexpr int NCT   = NCOL/4;
    constexpr int KT    = C*KWG*NKYG;
    constexpr int NFR   = NKYG + NDY - 1;
    __shared__ __align__(16) unsigned short smem[NCOL*RSTR];

    const int yb  = blockIdx.y;
    const int zz  = blockIdx.z;
    const int ksp = zz % nks;
    const int lb  = zz / nks;
    const int b   = b0 + lb;
    const int y0  = (yb >> 3)*(8*NDY) + (yb & 7);
    const int tid = threadIdx.x;
    const int lane = tid & 63;
    const int wv   = tid >> 6;
    const int g    = lane >> 4;
    const int lm   = lane & 15;
    const int rot  = (zz*7 + yb*3) & (KS-1);

    fx4 acc[NT][NDY];
    #pragma unroll
    for (int t = 0; t < NT; ++t)
        #pragma unroll
        for (int dy = 0; dy < NDY; ++dy) acc[t][dy] = (fx4){0.f, 0.f, 0.f, 0.f};

    const float* feat = feat_all + (size_t)b * C * H * W;
    const unsigned short* Wlane = Wswz + ((size_t)lb*KT)*512 + lane*8;

    // this thread's staging tile (one 8-row x 4-col transpose tile), 1/thread
    const bool sact = tid < NCT*NRT;
    const int rt = tid % NRT, ct = tid / NRT;
    const int col0 = ct*4, r0 = rt*8;
    const int sx0 = col0 - P;

    auto STAGE = [&](int c) {
        if (!sact) return;
        const float* src = feat + (size_t)c*H*W;
        float4 f[8];
        #pragma unroll
        for (int rr = 0; rr < 8; ++rr) {
            int y = y0 + r0 + rr - P;
            bool yok = (y >= 0) && (y < H);
            if (yok && sx0 >= 0 && sx0 + 3 < W) {
                f[rr] = *reinterpret_cast<const float4*>(src + (size_t)y*W + sx0);
            } else {
                float t4[4];
                #pragma unroll
                for (int j = 0; j < 4; ++j) {
                    int x = sx0 + j;
                    t4[j] = (yok && x >= 0 && x < W) ? src[(size_t)y*W + x] : 0.f;
                }
                f[rr] = make_float4(t4[0], t4[1], t4[2], t4[3]);
            }
        }
        #pragma unroll
        for (int j = 0; j < 4; ++j) {
            uint4 w4;
            w4.x = pk_bf16(((const float*)&f[0])[j], ((const float*)&f[1])[j]);
            w4.y = pk_bf16(((const float*)&f[2])[j], ((const float*)&f[3])[j]);
            w4.z = pk_bf16(((const float*)&f[4])[j], ((const float*)&f[5])[j]);
            w4.w = pk_bf16(((const float*)&f[6])[j], ((const float*)&f[7])[j]);
            *reinterpret_cast<uint4*>(smem + (col0 + j)*RSTR + r0) = w4;
        }
    };
    auto CHOF = [&](int i) { return ksp*KS + ((i + rot) & (KS-1)); };

    // prologue: stage first channel; preload its kxg=0 A-frags
    STAGE(CHOF(0));
    bfx8 afc[NKYG];
    {
        const unsigned short* W0 = Wlane + ((size_t)CHOF(0)*KWG)*NKYG*512;
        #pragma unroll
        for (int kyg = 0; kyg < NKYG; ++kyg)
            afc[kyg] = *reinterpret_cast<const bfx8*>(W0 + (size_t)kyg*512);
    }
    __syncthreads();

    #pragma unroll 1
    for (int ci = 0; ci < KS; ++ci) {
        #pragma unroll 2
        for (int kxg = 0; kxg < KWG; ++kxg) {
            // prefetch next (ch,kxg) A-frags (wraps harmlessly at the end)
            bfx8 afn[NKYG];
            {
                int ni = (kxg + 1 < KWG) ? ci : ci + 1;
                int nk = (kxg + 1 < KWG) ? kxg + 1 : 0;
                const unsigned short* Wn =
                    Wlane + (((size_t)CHOF(ni)*KWG + nk)*NKYG)*512;
                #pragma unroll
                for (int kyg = 0; kyg < NKYG; ++kyg)
                    afn[kyg] = *reinterpret_cast<const bfx8*>(Wn + (size_t)kyg*512);
            }
            #pragma unroll
            for (int t = 0; t < NT; ++t) {
                const unsigned short* bp =
                    smem + ((size_t)(t*64 + wv*16 + lm + g + kxg*4))*RSTR;
                bfx8 fr[NFR];
                #pragma unroll
                for (int rg = 0; rg < NFR; ++rg)
                    fr[rg] = *reinterpret_cast<const bfx8*>(bp + rg*8);
                __builtin_amdgcn_s_setprio(1);
                #pragma unroll
                for (int dy = 0; dy < NDY; ++dy)
                    #pragma unroll
                    for (int kyg = 0; kyg < NKYG; ++kyg)
                        acc[t][dy] = __builtin_amdgcn_mfma_f32_16x16x32_bf16(
                            afc[kyg], fr[kyg + dy], acc[t][dy], 0, 0, 0);
                __builtin_amdgcn_s_setprio(0);
            }
            #pragma unroll
            for (int kyg = 0; kyg < NKYG; ++kyg) afc[kyg] = afn[kyg];
        }
        __syncthreads();                       // reads of smem done
        if (ci + 1 < KS) STAGE(CHOF(ci + 1));
        __syncthreads();                       // writes visible
    }
    // ---- epilogue: D row = g*4+r = filter m (sc*N+n), col = lane&15 ----
    #pragma unroll
    for (int t = 0; t < NT; ++t) {
        const int x = t*64 + wv*16 + lm;
        #pragma unroll
        for (int dy = 0; dy < NDY; ++dy) {
            int y = y0 + dy*8;
            #pragma unroll
            for (int r = 0; r < 4; ++r) {
                int m  = g*4 + r;
                int sc = m / N;
                int n  = m - sc*N;
                if (sc < 3) {
                    size_t oi = ((((size_t)ksp*Btot + b)*N + n)*3 + sc)*((size_t)H*W)
                              + (size_t)y*W + x;
                    part[oi] = acc[t][dy][r];
                }
            }
        }
    }
}

// Sum m3 split-K partials -> out planes 0..2.
__global__ void k_reduce3(const float* __restrict__ part, float* __restrict__ out,
                          int B, int N, int nks) {
    int idx = blockIdx.x*256 + threadIdx.x;
    int tot = B*N*3*128*128;
    if (idx >= tot) return;
    int px = idx & 16383;
    int r = idx >> 14;
    int sc = r % 3; r /= 3;
    int n = r % N; int b = r / N;
    size_t stride = (size_t)B*N*3*16384;
    const float* p = part + ((size_t)(b*N + n)*3 + sc)*16384 + px;
    float s = 0.f;
    for (int ks = 0; ks < nks; ++ks) s += p[(size_t)ks*stride];
    out[(((size_t)(b*N + n)*6 + sc) << 14) + px] = s;
}

// Sum m4 split-K partials + 64->128 bilinear upsample -> out planes 3..5.
__global__ void k_upsample_sum(const float* __restrict__ part, float* __restrict__ out,
                               int B, int N, int nks) {
    int idx = blockIdx.x*256 + threadIdx.x;
    int tot = B*N*3*128*128;
    if (idx >= tot) return;
    int x = idx & 127; int r = idx >> 7;
    int y = r & 127; r >>= 7;
    int sc = r % 3; r /= 3;
    int n = r % N; int b = r / N;
    int y0, y1, x0, x1; float wy, wx;
    bl_w(y, 128, 64, y0, y1, wy);
    bl_w(x, 128, 64, x0, x1, wx);
    size_t stride = (size_t)B*N*3*4096;
    const float* p = part + ((size_t)(b*N + n)*3 + sc)*4096;
    float f00 = 0.f, f10 = 0.f, f01 = 0.f, f11 = 0.f;
    for (int ks = 0; ks < nks; ++ks) {
        const float* q = p + (size_t)ks*stride;
        f00 += q[y0*64 + x0]; f10 += q[y1*64 + x0];
        f01 += q[y0*64 + x1]; f11 += q[y1*64 + x1];
    }
    out[((size_t)((b*N + n)*6 + 3 + sc)*128 + y)*128 + x] =
        (f00*(1.f-wy) + f10*wy)*(1.f-wx) + (f01*(1.f-wy) + f11*wy)*wx;
}

extern "C" void kernel_launch(void* const* d_in, const int* in_sizes, int n_in,
                              void* d_out, int out_size, void* d_ws, size_t ws_size,
                              hipStream_t stream) {
    const float* map3 = (const float*)d_in[0];
    const float* map4 = (const float*)d_in[1];
    const int*   tlbr = (const int*)d_in[2];
    const int*   p_imgh = (const int*)d_in[3];
    const int*   p_imgw = (const int*)d_in[4];
    float* out = (float*)d_out;

    const int C3 = 512, H3 = 128, C4 = 1024, H4 = 64;
    int B = in_sizes[0] / (C3 * H3 * H3);
    int N = in_sizes[2] / (B * 4);
    int ms = 2 + 4*N + 6 + 6 + 2*N;
    const int NKS3 = 16, NKS4 = 64;

    // Workspace: meta (4KB) | part (split-K partials, shared m3/m4) | Wbuf
    char* wsp = (char*)d_ws;
    int* meta = (int*)wsp;
    size_t off = 4096;
    float* part = (float*)(wsp + off);
    size_t part_bytes = (size_t)NKS3 * B * N * 3 * H3 * H3 * 4;  // == m4's NKS4 partials
    off += part_bytes;
    unsigned short* Wbuf = (unsigned short*)(wsp + off);
    size_t wavail = (ws_size > off) ? (ws_size - off) : 0;
    size_t wpb = (size_t)9216 * 1024;   // KT3=512*6*3=9216 k-steps x 1KB
    int cb = (int)(wavail / wpb); if (cb > B) cb = B; if (cb < 1) cb = 1;

    k_meta<<<1, 1, 0, stream>>>(tlbr, p_imgh, p_imgw, B, N, ms, meta);

    { // ---- level 0 (m3): filters -> split-K NT=2/NDY=4 conv -> reduce ----
        for (int b0 = 0; b0 < B; b0 += cb) {
            int cbn = (cb < B - b0) ? cb : (B - b0);
            long long thr = (long long)cbn * 9216 * 64;
            k_filters<512,24,24,3><<<(int)((thr + 255) / 256), 256, 0, stream>>>(
                map3, meta, Wbuf, b0, cbn, N, 0, ms, H3, H3);
            dim3 grid(1, 32, cbn * NKS3);
            k_mfconv<512,32,24,24,128,128,3,4,2,56,152,12><<<grid, 256, 0, stream>>>(
                map3, Wbuf, part, b0, B, N, NKS3);
        }
        int tot = B * N * 3 * H3 * H3;
        k_reduce3<<<(tot + 255) / 256, 256, 0, stream>>>(part, out, B, N, NKS3);
    }
    { // ---- level 1 (m4): filters -> split-K NT=1/NDY=8 conv -> reduce+upsample ----
        for (int b0 = 0; b0 < B; b0 += cb) {
            int cbn = (cb < B - b0) ? cb : (B - b0);
            long long thr = (long long)cbn * 8192 * 64;
            k_filters<1024,16,16,2><<<(int)((thr + 255) / 256), 256, 0, stream>>>(
                map4, meta, Wbuf, b0, cbn, N, 1, ms, H4, H4);
            dim3 grid(1, 8, cbn * NKS4);
            k_mfconv<1024,16,16,16,64,64,2,8,1,72,80,8><<<grid, 256, 0, stream>>>(
                map4, Wbuf, part, b0, B, N, NKS4);
        }
        int tot = B * N * 3 * H3 * H3;
        k_upsample_sum<<<(tot + 255) / 256, 256, 0, stream>>>(part, out, B, N, NKS4);
    }
}